// Round 2
// baseline (284.698 us; speedup 1.0000x reference)
//
#include <hip/hip_runtime.h>

#define BB 64      // batch
#define CC 256     // query dim
#define DD 128     // key/value dim
#define NN 100000  // bank entries
#define KK 8       // top-k

#define CHUNK 128                         // keys per block (kernel B)
#define NBLK ((NN + CHUNK - 1) / CHUNK)   // 782
#define CPB (NBLK * KK)                   // candidates per row = 6256

__device__ __forceinline__ bool better(float v1, int i1, float v2, int i2) {
    return (v1 > v2) || (v1 == v2 && i1 < i2);
}

// sorted-descending insert into 8-list (register arrays, static indexing only)
__device__ __forceinline__ void sins8(float v, int ix, float lv[8], int li[8]) {
    if (!better(v, ix, lv[7], li[7])) return;
    lv[7] = v; li[7] = ix;
#pragma unroll
    for (int s = 7; s > 0; --s) {
        bool sw = better(lv[s], li[s], lv[s - 1], li[s - 1]);
        float tv = lv[s - 1]; int ti = li[s - 1];
        float nv = sw ? lv[s] : lv[s - 1]; int ni = sw ? li[s] : li[s - 1];
        lv[s] = sw ? tv : lv[s]; li[s] = sw ? ti : li[s];
        lv[s - 1] = nv; li[s - 1] = ni;
    }
}

// ---------------- Kernel A: q = query @ Wq^T + bq; qn_t[d][b] = l2norm(q) ----------------
__global__ __launch_bounds__(128) void qproj_kernel(
    const float* __restrict__ query,  // [64][256]
    const float* __restrict__ Wq,     // [128][256]
    const float* __restrict__ bq,     // [128]
    float* __restrict__ qn_t)         // [128][64] TRANSPOSED
{
    __shared__ float qrow[CC];
    __shared__ float red[DD];
    const int tid = threadIdx.x;
    const int b = blockIdx.x;
    for (int i = tid; i < CC; i += 128) qrow[i] = query[b * CC + i];
    __syncthreads();
    float acc = bq[tid];
    const float4* wr = reinterpret_cast<const float4*>(Wq + (size_t)tid * CC);
#pragma unroll 8
    for (int c = 0; c < CC / 4; ++c) {
        float4 w = wr[c];
        acc = fmaf(w.x, qrow[c * 4 + 0], acc);
        acc = fmaf(w.y, qrow[c * 4 + 1], acc);
        acc = fmaf(w.z, qrow[c * 4 + 2], acc);
        acc = fmaf(w.w, qrow[c * 4 + 3], acc);
    }
    red[tid] = acc * acc;
    __syncthreads();
    for (int s = 64; s > 0; s >>= 1) {
        if (tid < s) red[tid] += red[tid + s];
        __syncthreads();
    }
    float nrm = fmaxf(sqrtf(red[0]), 1e-12f);
    qn_t[tid * BB + b] = acc / nrm;
}

// ---------------- Kernel B: sim + per-chunk top-8 candidates ----------------
// 128 threads, one 128-key chunk per block, all 64 rows.
// Thread (ty=tid>>4, tx=tid&15): rows ty*8..+7, keys {tx*4+i, 64+tx*4+i}.
__global__ __launch_bounds__(128) void simtopk_kernel(
    const float* __restrict__ qn_t,   // [128][64]
    const float* __restrict__ keys,   // [N][128]
    const float* __restrict__ imp,    // [N]
    float* __restrict__ cand_v,       // [64][CPB]
    int* __restrict__ cand_i)
{
    // union: qn (128*64=8192 floats) while computing; sims (64*129=8256) after
    __shared__ float uni[64 * 129];      // 33024 B
    __shared__ float key_s[32 * 128];    // 16384 B, one d-slice of keys [ds][j]
    __shared__ float scale_s[CHUNK];     // importance/norm per key
    __shared__ float c2v[64][2][8];      // 4 KB
    __shared__ int   c2i[64][2][8];      // 4 KB

    const int tid = threadIdx.x;
    const int blk = blockIdx.x;
    const int key0 = blk * CHUNK;

    // load qn [d][r] (linear copy, coalesced, conflict-free)
    {
        float4* dst = reinterpret_cast<float4*>(uni);
        const float4* src = reinterpret_cast<const float4*>(qn_t);
        for (int i = tid; i < (DD * BB) / 4; i += 128) dst[i] = src[i];
    }

    const int ty = tid >> 4;   // 0..7
    const int tx = tid & 15;   // 0..15

    float acc[8][8];
#pragma unroll
    for (int r = 0; r < 8; ++r)
#pragma unroll
        for (int c = 0; c < 8; ++c) acc[r][c] = 0.f;

    float ss = 0.f;                 // key norm accumulator (this thread's key j)
    const int j = key0 + tid;       // one key per thread for staging

    for (int slice = 0; slice < 4; ++slice) {
        __syncthreads();  // qn ready (slice 0) / previous slice consumed
        if (j < NN) {
            const float4* krow = reinterpret_cast<const float4*>(keys + (size_t)j * DD + slice * 32);
#pragma unroll
            for (int c = 0; c < 8; ++c) {
                float4 v = krow[c];
                ss = fmaf(v.x, v.x, fmaf(v.y, v.y, fmaf(v.z, v.z, fmaf(v.w, v.w, ss))));
                key_s[(c * 4 + 0) * 128 + tid] = v.x;
                key_s[(c * 4 + 1) * 128 + tid] = v.y;
                key_s[(c * 4 + 2) * 128 + tid] = v.z;
                key_s[(c * 4 + 3) * 128 + tid] = v.w;
            }
        } else {
#pragma unroll
            for (int dsl = 0; dsl < 32; ++dsl) key_s[dsl * 128 + tid] = 0.f;
        }
        __syncthreads();

#pragma unroll 4
        for (int dsl = 0; dsl < 32; ++dsl) {
            const int d = slice * 32 + dsl;
            float4 q0 = *reinterpret_cast<const float4*>(&uni[d * 64 + ty * 8]);
            float4 q1 = *reinterpret_cast<const float4*>(&uni[d * 64 + ty * 8 + 4]);
            float4 k0 = *reinterpret_cast<const float4*>(&key_s[dsl * 128 + tx * 4]);
            float4 k1 = *reinterpret_cast<const float4*>(&key_s[dsl * 128 + 64 + tx * 4]);
            float qv[8] = {q0.x, q0.y, q0.z, q0.w, q1.x, q1.y, q1.z, q1.w};
            float kv[8] = {k0.x, k0.y, k0.z, k0.w, k1.x, k1.y, k1.z, k1.w};
#pragma unroll
            for (int r = 0; r < 8; ++r)
#pragma unroll
                for (int c = 0; c < 8; ++c)
                    acc[r][c] = fmaf(qv[r], kv[c], acc[r][c]);
        }
    }

    float myscale = 0.f;
    if (j < NN) myscale = imp[j] / fmaxf(sqrtf(ss), 1e-12f);
    __syncthreads();               // all compute done; uni (qn) is now dead
    scale_s[tid] = myscale;
    __syncthreads();               // scale_s visible

    // write scaled sims into uni[row*129 + jl] (pad 129 -> 2-way max on reads)
#pragma unroll
    for (int r = 0; r < 8; ++r) {
        const int row = ty * 8 + r;
#pragma unroll
        for (int half = 0; half < 2; ++half)
#pragma unroll
            for (int i2 = 0; i2 < 4; ++i2) {
                const int jl = half * 64 + tx * 4 + i2;
                const int jg = key0 + jl;
                float v = (jg < NN) ? acc[r][half * 4 + i2] * scale_s[jl] : -1e30f;
                uni[row * 129 + jl] = v;
            }
    }
    __syncthreads();

    // selection: 2 threads per row, each scans 64 sims
    {
        const int row = tid >> 1, h = tid & 1;
        float v8[8]; int i8[8];
#pragma unroll
        for (int s = 0; s < 8; ++s) { v8[s] = -1e30f; i8[s] = 0; }
        for (int t = 0; t < 64; ++t) {
            const int jl = h * 64 + t;
            sins8(uni[row * 129 + jl], key0 + jl, v8, i8);
        }
#pragma unroll
        for (int s = 0; s < 8; ++s) { c2v[row][h][s] = v8[s]; c2i[row][h][s] = i8[s]; }
    }
    __syncthreads();

    // final per-row merge (16 -> 8) and global write
    if (tid < 64) {
        const int row = tid;
        float v8[8]; int i8[8];
#pragma unroll
        for (int s = 0; s < 8; ++s) { v8[s] = -1e30f; i8[s] = 0; }
        for (int t = 0; t < 16; ++t)
            sins8(c2v[row][t >> 3][t & 7], c2i[row][t >> 3][t & 7], v8, i8);
        const size_t base = (size_t)row * CPB + (size_t)blk * KK;
#pragma unroll
        for (int s = 0; s < 8; ++s) { cand_v[base + s] = v8[s]; cand_i[base + s] = i8[s]; }
    }
}

// ---------------- Kernel C: merge candidates -> final top-8 indices per row ----------------
__global__ __launch_bounds__(256) void topkmerge_kernel(
    const float* __restrict__ cand_v, const int* __restrict__ cand_i,
    int* __restrict__ topk)
{
    __shared__ float lv[2048]; __shared__ int li[2048];
    __shared__ float c3v[64][8]; __shared__ int c3i[64][8];
    __shared__ float c4v[8][8]; __shared__ int c4i[8][8];
    const int tid = threadIdx.x;
    const int row = blockIdx.x;

    float v8[8]; int i8[8];
#pragma unroll
    for (int s = 0; s < 8; ++s) { v8[s] = -1e30f; i8[s] = 0; }
    for (int c = tid; c < CPB; c += 256)
        sins8(cand_v[(size_t)row * CPB + c], cand_i[(size_t)row * CPB + c], v8, i8);
#pragma unroll
    for (int s = 0; s < 8; ++s) { lv[tid * 8 + s] = v8[s]; li[tid * 8 + s] = i8[s]; }
    __syncthreads();
    if (tid < 64) {
#pragma unroll
        for (int s = 0; s < 8; ++s) { v8[s] = -1e30f; i8[s] = 0; }
        for (int t = 0; t < 32; ++t) sins8(lv[tid * 32 + t], li[tid * 32 + t], v8, i8);
#pragma unroll
        for (int s = 0; s < 8; ++s) { c3v[tid][s] = v8[s]; c3i[tid][s] = i8[s]; }
    }
    __syncthreads();
    if (tid < 8) {
        const float* fv = &c3v[0][0]; const int* fi = &c3i[0][0];
#pragma unroll
        for (int s = 0; s < 8; ++s) { v8[s] = -1e30f; i8[s] = 0; }
        for (int t = 0; t < 64; ++t) sins8(fv[tid * 64 + t], fi[tid * 64 + t], v8, i8);
#pragma unroll
        for (int s = 0; s < 8; ++s) { c4v[tid][s] = v8[s]; c4i[tid][s] = i8[s]; }
    }
    __syncthreads();
    if (tid == 0) {
        const float* fv = &c4v[0][0]; const int* fi = &c4i[0][0];
#pragma unroll
        for (int s = 0; s < 8; ++s) { v8[s] = -1e30f; i8[s] = 0; }
        for (int t = 0; t < 64; ++t) sins8(fv[t], fi[t], v8, i8);
#pragma unroll
        for (int s = 0; s < 8; ++s) topk[row * KK + s] = i8[s];
    }
}

// ---------------- Kernel D: gather + softmax attention + W_comb ----------------
__global__ __launch_bounds__(128) void finish_kernel(
    const float* __restrict__ values,  // [N][128]
    const float* __restrict__ w_attn,  // [128]
    const float* __restrict__ b_attn,  // [1]
    const float* __restrict__ W_comb,  // [128][128]
    const float* __restrict__ b_comb,  // [128]
    const int* __restrict__ topk,      // [64][8]
    float* __restrict__ out)           // [64][128]
{
    __shared__ float red[KK][DD];
    __shared__ float tvals[KK];
    __shared__ float mem[DD];
    const int tid = threadIdx.x;
    const int b = blockIdx.x;

    float v[KK];
#pragma unroll
    for (int k = 0; k < KK; ++k) {
        int idx = topk[b * KK + k];
        v[k] = values[(size_t)idx * DD + tid];
    }
    float wa = w_attn[tid];
#pragma unroll
    for (int k = 0; k < KK; ++k) red[k][tid] = v[k] * wa;
    __syncthreads();
    if (tid < KK) {
        float s = 0.f;
        for (int i = 0; i < DD; ++i) s += red[tid][i];
        tvals[tid] = s + b_attn[0];
    }
    __syncthreads();
    float m = tvals[0];
#pragma unroll
    for (int k = 1; k < KK; ++k) m = fmaxf(m, tvals[k]);
    float e[KK]; float se = 0.f;
#pragma unroll
    for (int k = 0; k < KK; ++k) { e[k] = expf(tvals[k] - m); se += e[k]; }
    float inv = 1.f / se;
    float md = 0.f;
#pragma unroll
    for (int k = 0; k < KK; ++k) md += (e[k] * inv) * v[k];
    mem[tid] = md;
    __syncthreads();
    // W_comb row straight from global (L2-resident after first blocks)
    float acc = b_comb[tid];
    const float4* wrow = reinterpret_cast<const float4*>(W_comb + (size_t)tid * DD);
#pragma unroll 8
    for (int c = 0; c < DD / 4; ++c) {
        float4 w = wrow[c];
        acc = fmaf(w.x, mem[c * 4 + 0], acc);
        acc = fmaf(w.y, mem[c * 4 + 1], acc);
        acc = fmaf(w.z, mem[c * 4 + 2], acc);
        acc = fmaf(w.w, mem[c * 4 + 3], acc);
    }
    out[b * DD + tid] = acc;
}

extern "C" void kernel_launch(void* const* d_in, const int* in_sizes, int n_in,
                              void* d_out, int out_size, void* d_ws, size_t ws_size,
                              hipStream_t stream) {
    const float* query  = (const float*)d_in[0];
    const float* keys   = (const float*)d_in[1];
    const float* values = (const float*)d_in[2];
    const float* imp    = (const float*)d_in[3];
    const float* Wq     = (const float*)d_in[4];
    const float* bq     = (const float*)d_in[5];
    const float* wattn  = (const float*)d_in[6];
    const float* battn  = (const float*)d_in[7];
    const float* Wcomb  = (const float*)d_in[8];
    const float* bcomb  = (const float*)d_in[9];

    float* qn_t   = (float*)d_ws;                  // 128*64 floats (transposed)
    float* cand_v = qn_t + DD * BB;                // 64*CPB floats
    int*   cand_i = (int*)(cand_v + (size_t)BB * CPB);
    int*   topk   = cand_i + (size_t)BB * CPB;     // 64*8 ints

    qproj_kernel<<<BB, 128, 0, stream>>>(query, Wq, bq, qn_t);
    simtopk_kernel<<<NBLK, 128, 0, stream>>>(qn_t, keys, imp, cand_v, cand_i);
    topkmerge_kernel<<<BB, 256, 0, stream>>>(cand_v, cand_i, topk);
    finish_kernel<<<BB, 128, 0, stream>>>(values, wattn, battn, Wcomb, bcomb, topk,
                                          (float*)d_out);
}

// Round 3
// 241.666 us; speedup vs baseline: 1.1781x; 1.1781x over previous
//
#include <hip/hip_runtime.h>

typedef __attribute__((ext_vector_type(8))) short short8;
typedef __attribute__((ext_vector_type(4))) float f32x4;

#define BB 64      // batch
#define CC 256     // query dim
#define DD 128     // key/value dim
#define NN 100000  // bank entries
#define KK 8       // top-k

#define CHUNK 128                         // keys per block (kernel B)
#define NBLK ((NN + CHUNK - 1) / CHUNK)   // 782
#define CPB (NBLK * KK)                   // candidates per row = 6256

__device__ __forceinline__ bool better(float v1, int i1, float v2, int i2) {
    return (v1 > v2) || (v1 == v2 && i1 < i2);
}

// sorted-descending insert into 8-list (register arrays, static indexing only)
__device__ __forceinline__ void sins8(float v, int ix, float lv[8], int li[8]) {
    if (!better(v, ix, lv[7], li[7])) return;
    lv[7] = v; li[7] = ix;
#pragma unroll
    for (int s = 7; s > 0; --s) {
        bool sw = better(lv[s], li[s], lv[s - 1], li[s - 1]);
        float tv = lv[s - 1]; int ti = li[s - 1];
        float nv = sw ? lv[s] : lv[s - 1]; int ni = sw ? li[s] : li[s - 1];
        lv[s] = sw ? tv : lv[s]; li[s] = sw ? ti : li[s];
        lv[s - 1] = nv; li[s - 1] = ni;
    }
}

// f32 -> bf16 bits, round-nearest-even
__device__ __forceinline__ unsigned short f2bf(float x) {
    unsigned u = __float_as_uint(x);
    unsigned r = u + 0x7fffu + ((u >> 16) & 1u);
    return (unsigned short)(r >> 16);
}

// split x into bf16 hi + bf16 lo (x ~= hi + lo, ~16-bit mantissa coverage)
__device__ __forceinline__ void split_bf(float x, unsigned short& h, unsigned short& l) {
    h = f2bf(x);
    float hf = __uint_as_float(((unsigned)h) << 16);
    l = f2bf(x - hf);
}

// ---------------- Kernel A: q = query @ Wq^T + bq (NO normalization needed:
// per-row scale does not change per-row top-k). Emit A-operand MFMA fragments
// split into bf16 hi/lo.  Frag layout (16x16x32): lane holds
// A[m = lane&15][k = (lane>>4)*8 + j], j=0..7.
// Storage: qA[(mt*4+ks)*64 + lane]*8 + j  (ushort), hi and lo arrays.
__global__ __launch_bounds__(128) void qproj_kernel(
    const float* __restrict__ query,  // [64][256]
    const float* __restrict__ Wq,     // [128][256]
    const float* __restrict__ bq,     // [128]
    unsigned short* __restrict__ qAhi, // [8192]
    unsigned short* __restrict__ qAlo) // [8192]
{
    __shared__ float qrow[CC];
    const int tid = threadIdx.x;   // = d
    const int b = blockIdx.x;
    for (int i = tid; i < CC; i += 128) qrow[i] = query[b * CC + i];
    __syncthreads();
    float acc = bq[tid];
    const float4* wr = reinterpret_cast<const float4*>(Wq + (size_t)tid * CC);
#pragma unroll 8
    for (int c = 0; c < CC / 4; ++c) {
        float4 w = wr[c];
        acc = fmaf(w.x, qrow[c * 4 + 0], acc);
        acc = fmaf(w.y, qrow[c * 4 + 1], acc);
        acc = fmaf(w.z, qrow[c * 4 + 2], acc);
        acc = fmaf(w.w, qrow[c * 4 + 3], acc);
    }
    unsigned short h, l;
    split_bf(acc, h, l);
    const int d = tid;
    const int mt = b >> 4, n = b & 15;
    const int ks = d >> 5, quad = (d >> 3) & 3, j = d & 7;
    const size_t fi = ((size_t)(mt * 4 + ks) * 64 + quad * 16 + n) * 8 + j;
    qAhi[fi] = h;
    qAlo[fi] = l;
}

// ---------------- Kernel B: bf16x3 MFMA sim + per-chunk top-8 ----------------
// 256 threads (4 waves). Block covers 128 keys; wave w handles keys
// [key0+w*32, +32) as 2 N-tiles of 16. Each wave holds ALL 64 q-rows as
// A fragments in registers (hi+lo = 128 VGPRs). B fragments come straight
// from global f32 keys, converted to bf16 hi/lo in-register.
// sims = (q . k) * imp_j / ||k_j||  (row scale dropped - ordering invariant).
__global__ __launch_bounds__(256, 2) void simtopk_kernel(
    const unsigned short* __restrict__ qAhi,
    const unsigned short* __restrict__ qAlo,
    const float* __restrict__ keys,   // [N][128]
    const float* __restrict__ imp,    // [N]
    float* __restrict__ cand_v,       // [64][CPB]
    int* __restrict__ cand_i)
{
    __shared__ float sims[64 * 132];      // 33792 B (also qA staging at start)
    __shared__ float c2v[64 * 33];        // 8448 B (stride 33: 2-way max)
    __shared__ int   c2i[64 * 33];        // 8448 B

    const int tid = threadIdx.x;
    const int w = tid >> 6;        // wave 0..3
    const int lane = tid & 63;
    const int blk = blockIdx.x;
    const int key0 = blk * CHUNK;

    // ---- phase 0: stage qA (hi 16KB + lo 16KB) into sims region ----
    {
        uint4* dst = reinterpret_cast<uint4*>(sims);
        const uint4* srcA = reinterpret_cast<const uint4*>(qAhi);
        const uint4* srcB = reinterpret_cast<const uint4*>(qAlo);
        for (int i = tid; i < 1024; i += 256) dst[i] = srcA[i];
        for (int i = tid; i < 1024; i += 256) dst[1024 + i] = srcB[i];
    }
    __syncthreads();

    // ---- phase 1: read A fragments into registers ----
    short8 Ah[4][4], Al[4][4];
    {
        const short8* S = reinterpret_cast<const short8*>(sims);
#pragma unroll
        for (int mt = 0; mt < 4; ++mt)
#pragma unroll
            for (int ks = 0; ks < 4; ++ks) {
                const int idx = (mt * 4 + ks) * 64 + lane;
                Ah[mt][ks] = S[idx];
                Al[mt][ks] = S[1024 + idx];
            }
    }
    __syncthreads();   // all frag reads done before sims region is overwritten

    const int n = lane & 15, quad = lane >> 4;

    // ---- phase 2: per N-tile GEMM (K=128 via 4 MFMA steps x 3 passes) ----
    for (int t = 0; t < 2; ++t) {
        const int j = key0 + w * 32 + t * 16 + n;
        const int jc = (j < NN) ? j : (NN - 1);
        const float* kbase = keys + (size_t)jc * DD + quad * 8;

        f32x4 acc[4];
#pragma unroll
        for (int mt = 0; mt < 4; ++mt) acc[mt] = (f32x4){0.f, 0.f, 0.f, 0.f};
        float ss = 0.f;

#pragma unroll
        for (int ks = 0; ks < 4; ++ks) {
            float4 b0 = *reinterpret_cast<const float4*>(kbase + ks * 32);
            float4 b1 = *reinterpret_cast<const float4*>(kbase + ks * 32 + 4);
            float bf[8] = {b0.x, b0.y, b0.z, b0.w, b1.x, b1.y, b1.z, b1.w};
            short8 Bh, Bl;
#pragma unroll
            for (int e = 0; e < 8; ++e) {
                ss = fmaf(bf[e], bf[e], ss);
                unsigned short hh, ll;
                split_bf(bf[e], hh, ll);
                Bh[e] = (short)hh;
                Bl[e] = (short)ll;
            }
#pragma unroll
            for (int mt = 0; mt < 4; ++mt) {
                acc[mt] = __builtin_amdgcn_mfma_f32_16x16x32_bf16(Ah[mt][ks], Bh, acc[mt], 0, 0, 0);
                acc[mt] = __builtin_amdgcn_mfma_f32_16x16x32_bf16(Ah[mt][ks], Bl, acc[mt], 0, 0, 0);
                acc[mt] = __builtin_amdgcn_mfma_f32_16x16x32_bf16(Al[mt][ks], Bh, acc[mt], 0, 0, 0);
            }
        }

        // key-norm: lane holds 32 of key j's 128 elems; reduce over quads
        ss += __shfl_xor(ss, 16);
        ss += __shfl_xor(ss, 32);
        const bool valid = (j < NN);
        float scale = 0.f;
        if (valid) scale = imp[j] / fmaxf(sqrtf(ss), 1e-12f);

        // D layout: col = lane&15 (key n), row = quad*4 + reg (+ mt*16)
#pragma unroll
        for (int mt = 0; mt < 4; ++mt)
#pragma unroll
            for (int r = 0; r < 4; ++r) {
                const int row = mt * 16 + quad * 4 + r;
                const float v = valid ? acc[mt][r] * scale : -1e30f;
                sims[row * 132 + w * 32 + t * 16 + n] = v;
            }
    }
    __syncthreads();

    // ---- phase 3: selection, 4 threads per row scan 32 keys each ----
    {
        const int row = tid >> 2, part = tid & 3;
        float v8[8]; int i8[8];
#pragma unroll
        for (int s = 0; s < 8; ++s) { v8[s] = -1e30f; i8[s] = 0; }
        for (int it = 0; it < 32; ++it) {
            const int jl = part * 32 + it;
            sins8(sims[row * 132 + jl], key0 + jl, v8, i8);
        }
#pragma unroll
        for (int s = 0; s < 8; ++s) {
            c2v[row * 33 + part * 8 + s] = v8[s];
            c2i[row * 33 + part * 8 + s] = i8[s];
        }
    }
    __syncthreads();

    // ---- phase 4: per-row merge 32 -> 8, write candidates ----
    if (tid < 64) {
        const int row = tid;
        float v8[8]; int i8[8];
#pragma unroll
        for (int s = 0; s < 8; ++s) { v8[s] = -1e30f; i8[s] = 0; }
        for (int u = 0; u < 32; ++u)
            sins8(c2v[row * 33 + u], c2i[row * 33 + u], v8, i8);
        const size_t base = (size_t)row * CPB + (size_t)blk * KK;
#pragma unroll
        for (int s = 0; s < 8; ++s) { cand_v[base + s] = v8[s]; cand_i[base + s] = i8[s]; }
    }
}

// ---------------- Kernel C: merge candidates -> final top-8 indices per row ----------------
__global__ __launch_bounds__(256) void topkmerge_kernel(
    const float* __restrict__ cand_v, const int* __restrict__ cand_i,
    int* __restrict__ topk)
{
    __shared__ float lv[2048]; __shared__ int li[2048];
    __shared__ float c3v[64][8]; __shared__ int c3i[64][8];
    __shared__ float c4v[8][8]; __shared__ int c4i[8][8];
    const int tid = threadIdx.x;
    const int row = blockIdx.x;

    float v8[8]; int i8[8];
#pragma unroll
    for (int s = 0; s < 8; ++s) { v8[s] = -1e30f; i8[s] = 0; }
    for (int c = tid; c < CPB; c += 256)
        sins8(cand_v[(size_t)row * CPB + c], cand_i[(size_t)row * CPB + c], v8, i8);
#pragma unroll
    for (int s = 0; s < 8; ++s) { lv[tid * 8 + s] = v8[s]; li[tid * 8 + s] = i8[s]; }
    __syncthreads();
    if (tid < 64) {
#pragma unroll
        for (int s = 0; s < 8; ++s) { v8[s] = -1e30f; i8[s] = 0; }
        for (int t = 0; t < 32; ++t) sins8(lv[tid * 32 + t], li[tid * 32 + t], v8, i8);
#pragma unroll
        for (int s = 0; s < 8; ++s) { c3v[tid][s] = v8[s]; c3i[tid][s] = i8[s]; }
    }
    __syncthreads();
    if (tid < 8) {
        const float* fv = &c3v[0][0]; const int* fi = &c3i[0][0];
#pragma unroll
        for (int s = 0; s < 8; ++s) { v8[s] = -1e30f; i8[s] = 0; }
        for (int t = 0; t < 64; ++t) sins8(fv[tid * 64 + t], fi[tid * 64 + t], v8, i8);
#pragma unroll
        for (int s = 0; s < 8; ++s) { c4v[tid][s] = v8[s]; c4i[tid][s] = i8[s]; }
    }
    __syncthreads();
    if (tid == 0) {
        const float* fv = &c4v[0][0]; const int* fi = &c4i[0][0];
#pragma unroll
        for (int s = 0; s < 8; ++s) { v8[s] = -1e30f; i8[s] = 0; }
        for (int t = 0; t < 64; ++t) sins8(fv[t], fi[t], v8, i8);
#pragma unroll
        for (int s = 0; s < 8; ++s) topk[row * KK + s] = i8[s];
    }
}

// ---------------- Kernel D: gather + softmax attention + W_comb ----------------
__global__ __launch_bounds__(128) void finish_kernel(
    const float* __restrict__ values,  // [N][128]
    const float* __restrict__ w_attn,  // [128]
    const float* __restrict__ b_attn,  // [1]
    const float* __restrict__ W_comb,  // [128][128]
    const float* __restrict__ b_comb,  // [128]
    const int* __restrict__ topk,      // [64][8]
    float* __restrict__ out)           // [64][128]
{
    __shared__ float red[KK][DD];
    __shared__ float tvals[KK];
    __shared__ float mem[DD];
    const int tid = threadIdx.x;
    const int b = blockIdx.x;

    float v[KK];
#pragma unroll
    for (int k = 0; k < KK; ++k) {
        int idx = topk[b * KK + k];
        v[k] = values[(size_t)idx * DD + tid];
    }
    float wa = w_attn[tid];
#pragma unroll
    for (int k = 0; k < KK; ++k) red[k][tid] = v[k] * wa;
    __syncthreads();
    if (tid < KK) {
        float s = 0.f;
        for (int i = 0; i < DD; ++i) s += red[tid][i];
        tvals[tid] = s + b_attn[0];
    }
    __syncthreads();
    float m = tvals[0];
#pragma unroll
    for (int k = 1; k < KK; ++k) m = fmaxf(m, tvals[k]);
    float e[KK]; float se = 0.f;
#pragma unroll
    for (int k = 0; k < KK; ++k) { e[k] = expf(tvals[k] - m); se += e[k]; }
    float inv = 1.f / se;
    float md = 0.f;
#pragma unroll
    for (int k = 0; k < KK; ++k) md += (e[k] * inv) * v[k];
    mem[tid] = md;
    __syncthreads();
    float acc = b_comb[tid];
    const float4* wrow = reinterpret_cast<const float4*>(W_comb + (size_t)tid * DD);
#pragma unroll 8
    for (int c = 0; c < DD / 4; ++c) {
        float4 wv = wrow[c];
        acc = fmaf(wv.x, mem[c * 4 + 0], acc);
        acc = fmaf(wv.y, mem[c * 4 + 1], acc);
        acc = fmaf(wv.z, mem[c * 4 + 2], acc);
        acc = fmaf(wv.w, mem[c * 4 + 3], acc);
    }
    out[b * DD + tid] = acc;
}

extern "C" void kernel_launch(void* const* d_in, const int* in_sizes, int n_in,
                              void* d_out, int out_size, void* d_ws, size_t ws_size,
                              hipStream_t stream) {
    const float* query  = (const float*)d_in[0];
    const float* keys   = (const float*)d_in[1];
    const float* values = (const float*)d_in[2];
    const float* imp    = (const float*)d_in[3];
    const float* Wq     = (const float*)d_in[4];
    const float* bq     = (const float*)d_in[5];
    const float* wattn  = (const float*)d_in[6];
    const float* battn  = (const float*)d_in[7];
    const float* Wcomb  = (const float*)d_in[8];
    const float* bcomb  = (const float*)d_in[9];

    unsigned short* qAhi = (unsigned short*)d_ws;          // 8192 ushort (16 KB)
    unsigned short* qAlo = qAhi + 8192;                    // 8192 ushort (16 KB)
    float* cand_v = (float*)(qAlo + 8192);                 // 64*CPB floats
    int*   cand_i = (int*)(cand_v + (size_t)BB * CPB);
    int*   topk   = cand_i + (size_t)BB * CPB;             // 64*8 ints

    qproj_kernel<<<BB, 128, 0, stream>>>(query, Wq, bq, qAhi, qAlo);
    simtopk_kernel<<<NBLK, 256, 0, stream>>>(qAhi, qAlo, keys, imp, cand_v, cand_i);
    topkmerge_kernel<<<BB, 256, 0, stream>>>(cand_v, cand_i, topk);
    finish_kernel<<<BB, 128, 0, stream>>>(values, wattn, battn, Wcomb, bcomb, topk,
                                          (float*)d_out);
}

// Round 4
// 171.040 us; speedup vs baseline: 1.6645x; 1.4129x over previous
//
#include <hip/hip_runtime.h>

typedef __attribute__((ext_vector_type(8))) short short8;
typedef __attribute__((ext_vector_type(4))) float f32x4;

#define BB 64      // batch
#define CC 256     // query dim
#define DD 128     // key/value dim
#define NN 100000  // bank entries
#define KK 8       // top-k

#define CHUNK 128                         // keys per block (kernel B)
#define NBLK ((NN + CHUNK - 1) / CHUNK)   // 782
#define CPB (NBLK * KK)                   // candidates per row = 6256

// f32 -> bf16 bits, round-nearest-even
__device__ __forceinline__ unsigned short f2bf(float x) {
    unsigned u = __float_as_uint(x);
    unsigned r = u + 0x7fffu + ((u >> 16) & 1u);
    return (unsigned short)(r >> 16);
}

// split x into bf16 hi + bf16 lo (RNE, x ~= hi + lo)
__device__ __forceinline__ void split_bf(float x, unsigned short& h, unsigned short& l) {
    h = f2bf(x);
    float hf = __uint_as_float(((unsigned)h) << 16);
    l = f2bf(x - hf);
}

// branchless sorted-descending top-8 insert, floats only (16 VALU, no branches)
__device__ __forceinline__ void bfins8(float x, float l[8]) {
#pragma unroll
    for (int s = 0; s < 8; ++s) {
        float hi = fmaxf(l[s], x);
        x = fminf(l[s], x);
        l[s] = hi;
    }
}

// branchless sorted-descending top-8 insert, (value,index) pairs
__device__ __forceinline__ void bpins8(float v, int ix, float lv[8], int li[8]) {
#pragma unroll
    for (int s = 0; s < 8; ++s) {
        const bool gt = v > lv[s];
        const float nv = gt ? lv[s] : v;
        const int   ni = gt ? li[s] : ix;
        lv[s] = gt ? v : lv[s];
        li[s] = gt ? ix : li[s];
        v = nv; ix = ni;
    }
}

// ---------------- Kernel A: q = query @ Wq^T + bq -> bf16 hi/lo A-fragments ----
// (row l2-norm dropped: per-row scale cannot change that row's top-k)
__global__ __launch_bounds__(128) void qproj_kernel(
    const float* __restrict__ query,  // [64][256]
    const float* __restrict__ Wq,     // [128][256]
    const float* __restrict__ bq,     // [128]
    unsigned short* __restrict__ qAhi, // [8192] fragment-ordered
    unsigned short* __restrict__ qAlo) // [8192]
{
    __shared__ float qrow[CC];
    const int tid = threadIdx.x;   // = d
    const int b = blockIdx.x;
    for (int i = tid; i < CC; i += 128) qrow[i] = query[b * CC + i];
    __syncthreads();
    float acc = bq[tid];
    const float4* wr = reinterpret_cast<const float4*>(Wq + (size_t)tid * CC);
#pragma unroll 8
    for (int c = 0; c < CC / 4; ++c) {
        float4 w = wr[c];
        acc = fmaf(w.x, qrow[c * 4 + 0], acc);
        acc = fmaf(w.y, qrow[c * 4 + 1], acc);
        acc = fmaf(w.z, qrow[c * 4 + 2], acc);
        acc = fmaf(w.w, qrow[c * 4 + 3], acc);
    }
    unsigned short h, l;
    split_bf(acc, h, l);
    // A-frag (16x16x32): lane holds A[m=lane&15][k=(lane>>4)*8+j]
    const int d = tid;
    const int mt = b >> 4, n = b & 15;
    const int ks = d >> 5, quad = (d >> 3) & 3, j = d & 7;
    const size_t fi = ((size_t)(mt * 4 + ks) * 64 + quad * 16 + n) * 8 + j;
    qAhi[fi] = h;
    qAlo[fi] = l;
}

// ---------------- Kernel B: bf16x3 MFMA sim + per-chunk top-8 (packed-float) ---
// 256 threads / 4 waves. Wave (p = w>>1, h = w&1): rows p*32..+31, keys
// key0 + h*64..+63 (4 N-tiles of 16). A-frags direct from global (L2).
// B-frags from global f32 keys, trunc-split to bf16 hi/lo in-register.
// sims packed: low 7 mantissa bits replaced by within-block key idx.
__global__ __launch_bounds__(256, 3) void simtopk_kernel(
    const unsigned short* __restrict__ qAhi,
    const unsigned short* __restrict__ qAlo,
    const float* __restrict__ keys,   // [N][128]
    const float* __restrict__ imp,    // [N]
    float* __restrict__ cand_v,       // [64][CPB] packed floats
    int* __restrict__ cand_i)         // [64][CPB] global key idx
{
    __shared__ float sims[64 * 132];  // 33792 B, packed sims
    __shared__ float c2v[64 * 33];    // 8448 B

    const int tid = threadIdx.x;
    const int w = tid >> 6, lane = tid & 63;
    const int p = w >> 1;          // row-pair group
    const int h = w & 1;           // key half
    const int blk = blockIdx.x;
    const int key0 = blk * CHUNK;
    const int n = lane & 15, quad = lane >> 4;

    // ---- A fragments straight from global ----
    short8 Ah[2][4], Al[2][4];
    {
        const short8* GH = reinterpret_cast<const short8*>(qAhi);
        const short8* GL = reinterpret_cast<const short8*>(qAlo);
#pragma unroll
        for (int m2 = 0; m2 < 2; ++m2)
#pragma unroll
            for (int ks = 0; ks < 4; ++ks) {
                const int idx = ((p * 2 + m2) * 4 + ks) * 64 + lane;
                Ah[m2][ks] = GH[idx];
                Al[m2][ks] = GL[idx];
            }
    }

    // ---- 4 N-tiles of 16 keys ----
#pragma unroll
    for (int t = 0; t < 4; ++t) {
        const int jl = h * 64 + t * 16 + n;
        const int j = key0 + jl;
        const int jc = (j < NN) ? j : (NN - 1);
        const float* kb = keys + (size_t)jc * DD + quad * 8;

        float4 bv[8];
#pragma unroll
        for (int ks = 0; ks < 4; ++ks) {
            bv[2 * ks]     = *reinterpret_cast<const float4*>(kb + ks * 32);
            bv[2 * ks + 1] = *reinterpret_cast<const float4*>(kb + ks * 32 + 4);
        }

        f32x4 acc[2];
        acc[0] = (f32x4){0.f, 0.f, 0.f, 0.f};
        acc[1] = (f32x4){0.f, 0.f, 0.f, 0.f};
        float ss = 0.f;

#pragma unroll
        for (int ks = 0; ks < 4; ++ks) {
            const float f[8] = {bv[2*ks].x, bv[2*ks].y, bv[2*ks].z, bv[2*ks].w,
                                bv[2*ks+1].x, bv[2*ks+1].y, bv[2*ks+1].z, bv[2*ks+1].w};
            unsigned hw[4], lw[4];
#pragma unroll
            for (int e = 0; e < 4; ++e) {
                const float f0 = f[2 * e], f1 = f[2 * e + 1];
                const unsigned u0 = __float_as_uint(f0), u1 = __float_as_uint(f1);
                // hi = truncate to bf16; pack two hi's with one v_perm
                hw[e] = __builtin_amdgcn_perm(u1, u0, 0x07060302u);
                // lo = truncate(x - hi) (exact sub; total err ~2^-16 rel)
                const float d0 = f0 - __uint_as_float(u0 & 0xffff0000u);
                const float d1 = f1 - __uint_as_float(u1 & 0xffff0000u);
                lw[e] = __builtin_amdgcn_perm(__float_as_uint(d1), __float_as_uint(d0), 0x07060302u);
                ss = fmaf(f0, f0, fmaf(f1, f1, ss));
            }
            uint4 hv = {hw[0], hw[1], hw[2], hw[3]};
            uint4 lv = {lw[0], lw[1], lw[2], lw[3]};
            short8 Bh = *reinterpret_cast<short8*>(&hv);
            short8 Bl = *reinterpret_cast<short8*>(&lv);
#pragma unroll
            for (int m2 = 0; m2 < 2; ++m2) {
                acc[m2] = __builtin_amdgcn_mfma_f32_16x16x32_bf16(Ah[m2][ks], Bh, acc[m2], 0, 0, 0);
                acc[m2] = __builtin_amdgcn_mfma_f32_16x16x32_bf16(Ah[m2][ks], Bl, acc[m2], 0, 0, 0);
                acc[m2] = __builtin_amdgcn_mfma_f32_16x16x32_bf16(Al[m2][ks], Bh, acc[m2], 0, 0, 0);
            }
        }

        // key norm: lane holds 32 of 128 elems; reduce across quads
        ss += __shfl_xor(ss, 16);
        ss += __shfl_xor(ss, 32);
        const bool valid = (j < NN);
        float scale = 0.f;
        if (valid) scale = imp[j] / fmaxf(sqrtf(ss), 1e-12f);

        // D layout: col = lane&15 (key), row = quad*4 + reg (+ m-tile*16)
#pragma unroll
        for (int m2 = 0; m2 < 2; ++m2)
#pragma unroll
            for (int r = 0; r < 4; ++r) {
                const int row = (p * 2 + m2) * 16 + quad * 4 + r;
                const float v = valid ? acc[m2][r] * scale : -1e30f;
                const unsigned packed = (__float_as_uint(v) & ~0x7Fu) | (unsigned)jl;
                sims[row * 132 + jl] = __uint_as_float(packed);
            }
    }
    __syncthreads();

    // ---- S1: 4 threads/row, each scans 32 keys (bank-staggered, 2-way max) ----
    {
        const int row = tid >> 2, part = tid & 3;
        float v8[8];
#pragma unroll
        for (int s = 0; s < 8; ++s) v8[s] = -1e30f;
        const int base = row * 132 + part * 32;
        const int st = ((row & 15) * 2 + part * 8) & 31;
        for (int i = 0; i < 32; ++i) {
            const int ia = (i + st) & 31;
            bfins8(sims[base + ia], v8);
        }
#pragma unroll
        for (int s = 0; s < 8; ++s) c2v[row * 33 + part * 8 + s] = v8[s];
    }
    __syncthreads();

    // ---- S2: 1 thread/row merges 32 -> 8, unpack idx, write candidates ----
    if (tid < 64) {
        const int row = tid;
        float v8[8];
#pragma unroll
        for (int s = 0; s < 8; ++s) v8[s] = -1e30f;
        for (int u = 0; u < 32; ++u) bfins8(c2v[row * 33 + u], v8);
        const size_t cbase = (size_t)row * CPB + (size_t)blk * KK;
#pragma unroll
        for (int s = 0; s < 8; ++s) {
            const unsigned bits = __float_as_uint(v8[s]);
            cand_v[cbase + s] = v8[s];
            cand_i[cbase + s] = key0 + (int)(bits & 127u);
        }
    }
}

// ---------------- Kernel CD: per-row candidate merge + attention + W_comb -----
__global__ __launch_bounds__(256) void mergefinish_kernel(
    const float* __restrict__ cand_v, const int* __restrict__ cand_i,
    const float* __restrict__ values,  // [N][128]
    const float* __restrict__ w_attn,  // [128]
    const float* __restrict__ b_attn,  // [1]
    const float* __restrict__ W_comb,  // [128][128]
    const float* __restrict__ b_comb,  // [128]
    float* __restrict__ out)           // [64][128]
{
    __shared__ float lv[256 * 8];
    __shared__ int   li[256 * 8];
    __shared__ int   tk[KK];
    __shared__ float red[KK][DD];
    __shared__ float tvals[KK];
    __shared__ float mem[DD];

    const int tid = threadIdx.x;
    const int row = blockIdx.x;

    // P1: 256 threads scan the row's 6256 candidates (coalesced, strided)
    {
        float v8[8]; int i8[8];
#pragma unroll
        for (int s = 0; s < 8; ++s) { v8[s] = -1e30f; i8[s] = 0; }
        const size_t base = (size_t)row * CPB;
        for (int c = tid; c < CPB; c += 256)
            bpins8(cand_v[base + c], cand_i[base + c], v8, i8);
#pragma unroll
        for (int s = 0; s < 8; ++s) { lv[tid * 8 + s] = v8[s]; li[tid * 8 + s] = i8[s]; }
    }
    __syncthreads();

    // P3+P4: wave 0 reduces 256 lists -> 64 lists -> top-8 via head extraction
    if (tid < 64) {
        float m8[8]; int mi8[8];
#pragma unroll
        for (int s = 0; s < 8; ++s) { m8[s] = -1e30f; mi8[s] = 0; }
        for (int k2 = 0; k2 < 4; ++k2)
#pragma unroll
            for (int s = 0; s < 8; ++s)
                bpins8(lv[(tid + 64 * k2) * 8 + s], li[(tid + 64 * k2) * 8 + s], m8, mi8);
        // 8 rounds of wave-wide head extraction (lists are sorted desc)
        for (int rd = 0; rd < KK; ++rd) {
            float m = m8[0];
#pragma unroll
            for (int d = 1; d < 64; d <<= 1) m = fmaxf(m, __shfl_xor(m, d));
            const unsigned long long msk = __ballot(m8[0] == m);
            const int wl = (int)(__ffsll((long long)msk) - 1);
            const int widx = __shfl(mi8[0], wl);
            if (tid == 0) tk[rd] = widx;
            if (tid == wl) {
#pragma unroll
                for (int s = 0; s < 7; ++s) { m8[s] = m8[s + 1]; mi8[s] = mi8[s + 1]; }
                m8[7] = -1e30f;
            }
        }
    }
    __syncthreads();

    // D phase: gather + softmax attention + W_comb (threads 0..127 active)
    float vk[KK];
    if (tid < 128) {
#pragma unroll
        for (int k = 0; k < KK; ++k)
            vk[k] = values[(size_t)tk[k] * DD + tid];
        const float wa = w_attn[tid];
#pragma unroll
        for (int k = 0; k < KK; ++k) red[k][tid] = vk[k] * wa;
    }
    __syncthreads();
    if (tid < KK) {
        float s = 0.f;
        for (int i = 0; i < DD; ++i) s += red[tid][i];
        tvals[tid] = s + b_attn[0];
    }
    __syncthreads();
    if (tid < 128) {
        float m = tvals[0];
#pragma unroll
        for (int k = 1; k < KK; ++k) m = fmaxf(m, tvals[k]);
        float e[KK]; float se = 0.f;
#pragma unroll
        for (int k = 0; k < KK; ++k) { e[k] = expf(tvals[k] - m); se += e[k]; }
        const float inv = 1.f / se;
        float md = 0.f;
#pragma unroll
        for (int k = 0; k < KK; ++k) md += (e[k] * inv) * vk[k];
        mem[tid] = md;
    }
    __syncthreads();
    if (tid < 128) {
        float acc = b_comb[tid];
        const float4* wrow = reinterpret_cast<const float4*>(W_comb + (size_t)tid * DD);
#pragma unroll 8
        for (int c = 0; c < DD / 4; ++c) {
            float4 wv = wrow[c];
            acc = fmaf(wv.x, mem[c * 4 + 0], acc);
            acc = fmaf(wv.y, mem[c * 4 + 1], acc);
            acc = fmaf(wv.z, mem[c * 4 + 2], acc);
            acc = fmaf(wv.w, mem[c * 4 + 3], acc);
        }
        out[row * DD + tid] = acc;
    }
}

extern "C" void kernel_launch(void* const* d_in, const int* in_sizes, int n_in,
                              void* d_out, int out_size, void* d_ws, size_t ws_size,
                              hipStream_t stream) {
    const float* query  = (const float*)d_in[0];
    const float* keys   = (const float*)d_in[1];
    const float* values = (const float*)d_in[2];
    const float* imp    = (const float*)d_in[3];
    const float* Wq     = (const float*)d_in[4];
    const float* bq     = (const float*)d_in[5];
    const float* wattn  = (const float*)d_in[6];
    const float* battn  = (const float*)d_in[7];
    const float* Wcomb  = (const float*)d_in[8];
    const float* bcomb  = (const float*)d_in[9];

    unsigned short* qAhi = (unsigned short*)d_ws;          // 8192 ushort (16 KB)
    unsigned short* qAlo = qAhi + 8192;                    // 8192 ushort (16 KB)
    float* cand_v = (float*)(qAlo + 8192);                 // 64*CPB floats
    int*   cand_i = (int*)(cand_v + (size_t)BB * CPB);     // 64*CPB ints

    qproj_kernel<<<BB, 128, 0, stream>>>(query, Wq, bq, qAhi, qAlo);
    simtopk_kernel<<<NBLK, 256, 0, stream>>>(qAhi, qAlo, keys, imp, cand_v, cand_i);
    mergefinish_kernel<<<BB, 256, 0, stream>>>(cand_v, cand_i, values, wattn, battn,
                                               Wcomb, bcomb, (float*)d_out);
}

// Round 5
// 163.084 us; speedup vs baseline: 1.7457x; 1.0488x over previous
//
#include <hip/hip_runtime.h>

typedef __attribute__((ext_vector_type(8))) short short8;
typedef __attribute__((ext_vector_type(4))) float f32x4;

#define BB 64      // batch
#define CC 256     // query dim
#define DD 128     // key/value dim
#define NN 100000  // bank entries
#define KK 8       // top-k

#define CHUNK 128                         // keys per block (kernel B)
#define NBLK ((NN + CHUNK - 1) / CHUNK)   // 782
#define CPB (NBLK * KK)                   // candidates per row = 6256

// f32 -> bf16 bits, round-nearest-even
__device__ __forceinline__ unsigned short f2bf(float x) {
    unsigned u = __float_as_uint(x);
    unsigned r = u + 0x7fffu + ((u >> 16) & 1u);
    return (unsigned short)(r >> 16);
}

// split x into bf16 hi + bf16 lo (RNE, x ~= hi + lo)
__device__ __forceinline__ void split_bf(float x, unsigned short& h, unsigned short& l) {
    h = f2bf(x);
    float hf = __uint_as_float(((unsigned)h) << 16);
    l = f2bf(x - hf);
}

// branchless sorted-descending top-8 insert, floats only (16 VALU, no branches)
__device__ __forceinline__ void bfins8(float x, float l[8]) {
#pragma unroll
    for (int s = 0; s < 8; ++s) {
        float hi = fmaxf(l[s], x);
        x = fminf(l[s], x);
        l[s] = hi;
    }
}

// branchless sorted-descending top-8 insert, (value,index) pairs
__device__ __forceinline__ void bpins8(float v, int ix, float lv[8], int li[8]) {
#pragma unroll
    for (int s = 0; s < 8; ++s) {
        const bool gt = v > lv[s];
        const float nv = gt ? lv[s] : v;
        const int   ni = gt ? li[s] : ix;
        lv[s] = gt ? v : lv[s];
        li[s] = gt ? ix : li[s];
        v = nv; ix = ni;
    }
}

// ---------------- Kernel A: q = query @ Wq^T + bq -> bf16 hi/lo A-fragments ----
// (row l2-norm dropped: per-row scale cannot change that row's top-k)
__global__ __launch_bounds__(128) void qproj_kernel(
    const float* __restrict__ query,  // [64][256]
    const float* __restrict__ Wq,     // [128][256]
    const float* __restrict__ bq,     // [128]
    unsigned short* __restrict__ qAhi, // [8192] fragment-ordered
    unsigned short* __restrict__ qAlo) // [8192]
{
    __shared__ float qrow[CC];
    const int tid = threadIdx.x;   // = d
    const int b = blockIdx.x;
    for (int i = tid; i < CC; i += 128) qrow[i] = query[b * CC + i];
    __syncthreads();
    float acc = bq[tid];
    const float4* wr = reinterpret_cast<const float4*>(Wq + (size_t)tid * CC);
#pragma unroll 8
    for (int c = 0; c < CC / 4; ++c) {
        float4 w = wr[c];
        acc = fmaf(w.x, qrow[c * 4 + 0], acc);
        acc = fmaf(w.y, qrow[c * 4 + 1], acc);
        acc = fmaf(w.z, qrow[c * 4 + 2], acc);
        acc = fmaf(w.w, qrow[c * 4 + 3], acc);
    }
    unsigned short h, l;
    split_bf(acc, h, l);
    // A-frag (16x16x32): lane holds A[m=lane&15][k=(lane>>4)*8+j]
    const int d = tid;
    const int mt = b >> 4, n = b & 15;
    const int ks = d >> 5, quad = (d >> 3) & 3, j = d & 7;
    const size_t fi = ((size_t)(mt * 4 + ks) * 64 + quad * 16 + n) * 8 + j;
    qAhi[fi] = h;
    qAlo[fi] = l;
}

// ---------------- Kernel B: bf16x3 MFMA sim + per-chunk top-8 (packed-float) ---
// 256 threads / 4 waves, 4 blocks/CU (33.8 KB LDS). Wave (p=w>>1, h=w&1):
// rows p*32..+31, keys key0+h*64..+63 (4 N-tiles of 16). A-frags direct from
// global (L2). B-frags from global f32 keys, trunc-split to bf16 hi/lo.
// sims packed: low 7 mantissa bits hold the within-block key idx; candidate
// block id is implicit in the output position (cand_i eliminated).
__global__ __launch_bounds__(256, 4) void simtopk_kernel(
    const unsigned short* __restrict__ qAhi,
    const unsigned short* __restrict__ qAlo,
    const float* __restrict__ keys,   // [N][128]
    const float* __restrict__ imp,    // [N]
    float* __restrict__ cand_v)       // [64][CPB] packed floats
{
    __shared__ float sims[64 * 132];  // 33792 B (sims; then partial lists)

    const int tid = threadIdx.x;
    const int w = tid >> 6, lane = tid & 63;
    const int p = w >> 1;          // row-pair group
    const int h = w & 1;           // key half
    const int blk = blockIdx.x;
    const int key0 = blk * CHUNK;
    const int n = lane & 15, quad = lane >> 4;

    // ---- A fragments straight from global ----
    short8 Ah[2][4], Al[2][4];
    {
        const short8* GH = reinterpret_cast<const short8*>(qAhi);
        const short8* GL = reinterpret_cast<const short8*>(qAlo);
#pragma unroll
        for (int m2 = 0; m2 < 2; ++m2)
#pragma unroll
            for (int ks = 0; ks < 4; ++ks) {
                const int idx = ((p * 2 + m2) * 4 + ks) * 64 + lane;
                Ah[m2][ks] = GH[idx];
                Al[m2][ks] = GL[idx];
            }
    }

    // ---- 4 N-tiles of 16 keys ----
#pragma unroll
    for (int t = 0; t < 4; ++t) {
        const int jl = h * 64 + t * 16 + n;
        const int j = key0 + jl;
        const int jc = (j < NN) ? j : (NN - 1);
        const float* kb = keys + (size_t)jc * DD + quad * 8;

        float4 bv[8];
#pragma unroll
        for (int ks = 0; ks < 4; ++ks) {
            bv[2 * ks]     = *reinterpret_cast<const float4*>(kb + ks * 32);
            bv[2 * ks + 1] = *reinterpret_cast<const float4*>(kb + ks * 32 + 4);
        }

        f32x4 acc[2];
        acc[0] = (f32x4){0.f, 0.f, 0.f, 0.f};
        acc[1] = (f32x4){0.f, 0.f, 0.f, 0.f};
        float ss = 0.f;

#pragma unroll
        for (int ks = 0; ks < 4; ++ks) {
            const float f[8] = {bv[2*ks].x, bv[2*ks].y, bv[2*ks].z, bv[2*ks].w,
                                bv[2*ks+1].x, bv[2*ks+1].y, bv[2*ks+1].z, bv[2*ks+1].w};
            unsigned hw[4], lw[4];
#pragma unroll
            for (int e = 0; e < 4; ++e) {
                const float f0 = f[2 * e], f1 = f[2 * e + 1];
                const unsigned u0 = __float_as_uint(f0), u1 = __float_as_uint(f1);
                hw[e] = __builtin_amdgcn_perm(u1, u0, 0x07060302u);
                const float d0 = f0 - __uint_as_float(u0 & 0xffff0000u);
                const float d1 = f1 - __uint_as_float(u1 & 0xffff0000u);
                lw[e] = __builtin_amdgcn_perm(__float_as_uint(d1), __float_as_uint(d0), 0x07060302u);
                ss = fmaf(f0, f0, fmaf(f1, f1, ss));
            }
            uint4 hv = {hw[0], hw[1], hw[2], hw[3]};
            uint4 lv = {lw[0], lw[1], lw[2], lw[3]};
            short8 Bh = *reinterpret_cast<short8*>(&hv);
            short8 Bl = *reinterpret_cast<short8*>(&lv);
#pragma unroll
            for (int m2 = 0; m2 < 2; ++m2) {
                acc[m2] = __builtin_amdgcn_mfma_f32_16x16x32_bf16(Ah[m2][ks], Bh, acc[m2], 0, 0, 0);
                acc[m2] = __builtin_amdgcn_mfma_f32_16x16x32_bf16(Ah[m2][ks], Bl, acc[m2], 0, 0, 0);
                acc[m2] = __builtin_amdgcn_mfma_f32_16x16x32_bf16(Al[m2][ks], Bh, acc[m2], 0, 0, 0);
            }
        }

        // key norm: lane holds 32 of 128 elems; reduce across quads
        ss += __shfl_xor(ss, 16);
        ss += __shfl_xor(ss, 32);
        const bool valid = (j < NN);
        float scale = 0.f;
        if (valid) scale = imp[j] / fmaxf(sqrtf(ss), 1e-12f);

        // D layout: col = lane&15 (key), row = quad*4 + reg (+ m-tile*16)
#pragma unroll
        for (int m2 = 0; m2 < 2; ++m2)
#pragma unroll
            for (int r = 0; r < 4; ++r) {
                const int row = (p * 2 + m2) * 16 + quad * 4 + r;
                const float v = valid ? acc[m2][r] * scale : -1e30f;
                const unsigned packed = (__float_as_uint(v) & ~0x7Fu) | (unsigned)jl;
                sims[row * 132 + jl] = __uint_as_float(packed);
            }
    }
    __syncthreads();

    // ---- S1: 4 threads/row, each scans 32 keys (staggered: exactly 2-way) ----
    float v8[8];
    {
        const int row = tid >> 2, part = tid & 3;
#pragma unroll
        for (int s = 0; s < 8; ++s) v8[s] = -1e30f;
        const int base = row * 132 + part * 32;
        const int st = ((row & 15) + part * 8) & 31;
        for (int i = 0; i < 32; ++i) {
            const int ia = (i + st) & 31;
            bfins8(sims[base + ia], v8);
        }
    }
    __syncthreads();   // all S1 reads complete; sims region reusable

    // ---- write partial lists back into sims (float4, aligned) ----
    {
        const int row = tid >> 2, part = tid & 3;
        float4* dst = reinterpret_cast<float4*>(&sims[row * 132 + part * 8]);
        dst[0] = (float4){v8[0], v8[1], v8[2], v8[3]};
        dst[1] = (float4){v8[4], v8[5], v8[6], v8[7]};
    }
    __syncthreads();

    // ---- S2: 1 thread/row merges 32 -> 8, write candidates (float4) ----
    if (tid < 64) {
        const int row = tid;
        float m8[8];
#pragma unroll
        for (int s = 0; s < 8; ++s) m8[s] = -1e30f;
        const int st = (3 * row) & 31;
        for (int u = 0; u < 32; ++u)
            bfins8(sims[row * 132 + ((u + st) & 31)], m8);
        float4* out4 = reinterpret_cast<float4*>(cand_v + (size_t)row * CPB + (size_t)blk * KK);
        out4[0] = (float4){m8[0], m8[1], m8[2], m8[3]};
        out4[1] = (float4){m8[4], m8[5], m8[6], m8[7]};
    }
}

// ---------------- Kernel CD: per-row candidate merge + attention + W_comb -----
__global__ __launch_bounds__(256) void mergefinish_kernel(
    const float* __restrict__ cand_v,  // [64][CPB] packed floats
    const float* __restrict__ values,  // [N][128]
    const float* __restrict__ w_attn,  // [128]
    const float* __restrict__ b_attn,  // [1]
    const float* __restrict__ W_comb,  // [128][128]
    const float* __restrict__ b_comb,  // [128]
    float* __restrict__ out)           // [64][128]
{
    __shared__ float lv[256 * 8];
    __shared__ int   li[256 * 8];
    __shared__ int   tk[KK];
    __shared__ float red[KK][DD];
    __shared__ float tvals[KK];
    __shared__ float mem[DD];

    const int tid = threadIdx.x;
    const int row = blockIdx.x;

    // P1: 256 threads scan the row's 6256 candidates (float4, coalesced)
    {
        float v8[8]; int i8[8];
#pragma unroll
        for (int s = 0; s < 8; ++s) { v8[s] = -1e30f; i8[s] = 0; }
        const float4* cv4 = reinterpret_cast<const float4*>(cand_v + (size_t)row * CPB);
        for (int c4 = tid; c4 < CPB / 4; c4 += 256) {
            const float4 v = cv4[c4];
            const int c = c4 * 4;
            bpins8(v.x, c + 0, v8, i8);
            bpins8(v.y, c + 1, v8, i8);
            bpins8(v.z, c + 2, v8, i8);
            bpins8(v.w, c + 3, v8, i8);
        }
#pragma unroll
        for (int s = 0; s < 8; ++s) { lv[tid * 8 + s] = v8[s]; li[tid * 8 + s] = i8[s]; }
    }
    __syncthreads();

    // P2: wave 0 reduces 256 lists -> 64 lists -> top-8 via head extraction.
    // Candidate position c decodes to key idx: (c>>3)*CHUNK + (bits(v)&127).
    if (tid < 64) {
        float m8[8]; int mi8[8];
#pragma unroll
        for (int s = 0; s < 8; ++s) { m8[s] = -1e30f; mi8[s] = 0; }
        for (int k2 = 0; k2 < 4; ++k2)
#pragma unroll
            for (int s = 0; s < 8; ++s)
                bpins8(lv[(tid + 64 * k2) * 8 + s], li[(tid + 64 * k2) * 8 + s], m8, mi8);
        for (int rd = 0; rd < KK; ++rd) {
            float m = m8[0];
#pragma unroll
            for (int d = 1; d < 64; d <<= 1) m = fmaxf(m, __shfl_xor(m, d));
            const unsigned long long msk = __ballot(m8[0] == m);
            const int wl = (int)(__ffsll((long long)msk) - 1);
            const int wc = __shfl(mi8[0], wl);
            if (tid == 0)
                tk[rd] = (wc >> 3) * CHUNK + (int)(__float_as_uint(m) & 127u);
            if (tid == wl) {
#pragma unroll
                for (int s = 0; s < 7; ++s) { m8[s] = m8[s + 1]; mi8[s] = mi8[s + 1]; }
                m8[7] = -1e30f;
            }
        }
    }
    __syncthreads();

    // D phase: gather + softmax attention + W_comb (threads 0..127 active)
    float vk[KK];
    if (tid < 128) {
#pragma unroll
        for (int k = 0; k < KK; ++k)
            vk[k] = values[(size_t)tk[k] * DD + tid];
        const float wa = w_attn[tid];
#pragma unroll
        for (int k = 0; k < KK; ++k) red[k][tid] = vk[k] * wa;
    }
    __syncthreads();
    if (tid < KK) {
        float s = 0.f;
        for (int i = 0; i < DD; ++i) s += red[tid][i];
        tvals[tid] = s + b_attn[0];
    }
    __syncthreads();
    if (tid < 128) {
        float m = tvals[0];
#pragma unroll
        for (int k = 1; k < KK; ++k) m = fmaxf(m, tvals[k]);
        float e[KK]; float se = 0.f;
#pragma unroll
        for (int k = 0; k < KK; ++k) { e[k] = expf(tvals[k] - m); se += e[k]; }
        const float inv = 1.f / se;
        float md = 0.f;
#pragma unroll
        for (int k = 0; k < KK; ++k) md += (e[k] * inv) * vk[k];
        mem[tid] = md;
    }
    __syncthreads();
    if (tid < 128) {
        float acc = b_comb[tid];
        const float4* wrow = reinterpret_cast<const float4*>(W_comb + (size_t)tid * DD);
#pragma unroll 8
        for (int c = 0; c < DD / 4; ++c) {
            float4 wv = wrow[c];
            acc = fmaf(wv.x, mem[c * 4 + 0], acc);
            acc = fmaf(wv.y, mem[c * 4 + 1], acc);
            acc = fmaf(wv.z, mem[c * 4 + 2], acc);
            acc = fmaf(wv.w, mem[c * 4 + 3], acc);
        }
        out[row * DD + tid] = acc;
    }
}

extern "C" void kernel_launch(void* const* d_in, const int* in_sizes, int n_in,
                              void* d_out, int out_size, void* d_ws, size_t ws_size,
                              hipStream_t stream) {
    const float* query  = (const float*)d_in[0];
    const float* keys   = (const float*)d_in[1];
    const float* values = (const float*)d_in[2];
    const float* imp    = (const float*)d_in[3];
    const float* Wq     = (const float*)d_in[4];
    const float* bq     = (const float*)d_in[5];
    const float* wattn  = (const float*)d_in[6];
    const float* battn  = (const float*)d_in[7];
    const float* Wcomb  = (const float*)d_in[8];
    const float* bcomb  = (const float*)d_in[9];

    unsigned short* qAhi = (unsigned short*)d_ws;          // 8192 ushort (16 KB)
    unsigned short* qAlo = qAhi + 8192;                    // 8192 ushort (16 KB)
    float* cand_v = (float*)(qAlo + 8192);                 // 64*CPB floats (1.6 MB)

    qproj_kernel<<<BB, 128, 0, stream>>>(query, Wq, bq, qAhi, qAlo);
    simtopk_kernel<<<NBLK, 256, 0, stream>>>(qAhi, qAlo, keys, imp, cand_v);
    mergefinish_kernel<<<BB, 256, 0, stream>>>(cand_v, values, wattn, battn,
                                               Wcomb, bcomb, (float*)d_out);
}